// Round 5
// baseline (502.414 us; speedup 1.0000x reference)
//
#include <hip/hip_runtime.h>
#include <hip/hip_bf16.h>

// ---- problem dims (fixed) ----
#define Bdim 4
#define Ldim 512
#define Ddim 768
#define Kspan 96
#define Hdim 3072
#define Pdim 9120      // Kspan*(Kspan-1)
#define MROWS 384      // Bdim*Kspan
#define NKT4 48        // Hdim/64: K-tiles for pair kernel (BK=64)

typedef __bf16 bf16x8 __attribute__((ext_vector_type(8)));
typedef float f32x4 __attribute__((ext_vector_type(4)));
typedef float f32x16 __attribute__((ext_vector_type(16)));
typedef unsigned short ushort8v __attribute__((ext_vector_type(8)));

static __device__ __forceinline__ unsigned short f2bf(float x){
  return __builtin_bit_cast(unsigned short, (__bf16)x);
}
static __device__ __forceinline__ float bf2f(unsigned short u){
  return (float)__builtin_bit_cast(__bf16, u);
}
static __device__ __forceinline__ float bfbits2f(unsigned short u){
  return __builtin_bit_cast(float, (unsigned)u << 16);
}

// ---------------- merged transpose+split: W[K][N] f32 -> WT[N][K] bf16 hi+lo -------------
struct TJob { const float* W; unsigned short* Th; unsigned short* Tl; int K; int N; int base; };
struct TJobs { TJob j[7]; };

__global__ __launch_bounds__(256) void transpose_multi(TJobs JJ)
{
  int x = blockIdx.x;
  int ji = 0;
  #pragma unroll
  for (int q = 1; q < 7; q++) if (x >= JJ.j[q].base) ji = q;
  TJob J = JJ.j[ji];
  int local = x - J.base;
  int tilesX = J.N >> 6;
  int bx = local % tilesX, by = local / tilesX;
  __shared__ float tile[64][65];
  int k0 = by * 64, n0 = bx * 64;
  int c = threadIdx.x & 63, r0 = threadIdx.x >> 6;
  for (int p = 0; p < 16; p++){
    int r = r0 + p * 4;
    tile[c][r] = J.W[(size_t)(k0 + r) * J.N + n0 + c];
  }
  __syncthreads();
  for (int p = 0; p < 16; p++){
    int n = r0 + p * 4;
    float xv = tile[n][c];
    unsigned short h = f2bf(xv);
    size_t o = (size_t)(n0 + n) * J.K + k0 + c;
    J.Th[o] = h;
    J.Tl[o] = f2bf(xv - bf2f(h));
  }
}

// ---------------- pack ro_w2 [Hdim][Ddim] f32 -> W2P bf16, pre-swizzled ------------------
// Tile (nq in 0..5, kt in 0..47): 128 n-rows x 64 k shorts, 128B rows.
// Phys short index o: n = o>>6, kph = o&63, logical ks = kph ^ ((n&7)<<3)  (involution).
__global__ __launch_bounds__(256) void pack_w2(
    const float* __restrict__ W, unsigned short* __restrict__ W2P)
{
  __shared__ float tile[64][129];
  int kt = blockIdx.x, nq = blockIdx.y, t = threadIdx.x;
  for (int q = 0; q < 32; q++){
    int flat = q * 256 + t;             // 0..8191
    int ks = flat >> 7, n = flat & 127;
    tile[ks][n] = W[(size_t)(kt * 64 + ks) * Ddim + nq * 128 + n];
  }
  __syncthreads();
  unsigned short* outp = W2P + (size_t)(nq * 48 + kt) * 8192;
  for (int q = 0; q < 32; q++){
    int o = q * 256 + t;
    int n = o >> 6, kph = o & 63;
    int ks = kph ^ ((n & 7) << 3);
    outp[o] = f2bf(tile[ks][n]);
  }
}

// ---------------- pack Vbuf f32 [MROWS][Hdim] -> Vp bf16 per (b,kt), pre-swizzled --------
// Tile (b, kt): 96 j-rows x 64 k shorts, 128B rows, same XOR swizzle on 8-short granules.
__global__ __launch_bounds__(256) void pack_v(
    const float* __restrict__ Vbuf, unsigned short* __restrict__ Vp)
{
  int kt = blockIdx.x, b = blockIdx.y, t = threadIdx.x;
  unsigned short* outp = Vp + (size_t)(b * 48 + kt) * 6144;
  #pragma unroll
  for (int q = 0; q < 3; q++){
    int item = q * 256 + t;             // 0..767
    int j = item >> 3, g = item & 7;
    const float* src = Vbuf + (size_t)(b * 96 + j) * Hdim + kt * 64 + g * 8;
    f32x4 a0 = *(const f32x4*)src, a1 = *(const f32x4*)(src + 4);
    ushort8v pk;
    #pragma unroll
    for (int e = 0; e < 4; e++) pk[e] = f2bf(a0[e]);
    #pragma unroll
    for (int e = 0; e < 4; e++) pk[e + 4] = f2bf(a1[e]);
    *(ushort8v*)(outp + j * 64 + ((g ^ (j & 7)) << 3)) = pk;
  }
}

// ---------------- gather h rows at span indices (fp32 copy) ----------------
__global__ __launch_bounds__(256) void gather_rows(
    const float* __restrict__ h, const int* __restrict__ span, float* __restrict__ hg)
{
  int x = blockIdx.x;            // 0 .. 2*MROWS-1
  int sel = (x >= MROWS) ? 1 : 0;
  int r = x - sel * MROWS;
  int b = r / Kspan, k = r - b * Kspan;
  int idx = span[(b * Kspan + k) * 2 + sel];
  const float* src = h + ((size_t)b * Ldim + idx) * Ddim;
  float* dst = hg + (size_t)x * Ddim;
  for (int d = threadIdx.x; d < Ddim; d += 256) dst[d] = src[d];
}

// ---------------- split-bf16 GEMM (multi-job + optional split-K) ------------------------
struct GJob {
  const float* A;
  const unsigned short* Wh;
  const unsigned short* Wl;
  const float* bias;
  float* C;
};

template<int MODE, int SPLIT>
__global__ __launch_bounds__(256) void gemm_ms(
    GJob j0, GJob j1, int ldA, int ldW, int ldC, int kLen, size_t csz)
{
  constexpr int SR = 40;
  __shared__ __align__(16) unsigned short Ah[64 * SR], Al[64 * SR];
  __shared__ __align__(16) unsigned short Bh[128 * SR], Bl[128 * SR];
  int zj, s;
  if (SPLIT == 1){ zj = blockIdx.z; s = 0; }
  else { zj = blockIdx.z / SPLIT; s = blockIdx.z % SPLIT; }
  const GJob J = zj ? j1 : j0;
  int kBegin = s * kLen;
  float* Cptr = (MODE == 2) ? (J.C + (size_t)s * csz) : J.C;

  int m0 = blockIdx.y * 64, n0 = blockIdx.x * 128;
  int t = threadIdx.x, lane = t & 63, wid = t >> 6;
  int wm = wid >> 1, wn = wid & 1;
  int lr = lane & 15, lk = (lane >> 4) * 8;
  f32x4 acc[2][4] = {};
  int ar = t >> 2, akq = t & 3;
  for (int k0 = 0; k0 < kLen; k0 += 32){
    {
      const float* sp = J.A + (size_t)(m0 + ar) * ldA + kBegin + k0 + akq * 8;
      f32x4 x0 = *(const f32x4*)sp, x1 = *(const f32x4*)(sp + 4);
      ushort8v vh, vl;
      for (int e = 0; e < 4; e++){ float x = x0[e]; unsigned short hh = f2bf(x); vh[e] = hh; vl[e] = f2bf(x - bf2f(hh)); }
      for (int e = 0; e < 4; e++){ float x = x1[e]; unsigned short hh = f2bf(x); vh[e+4] = hh; vl[e+4] = f2bf(x - bf2f(hh)); }
      *(ushort8v*)&Ah[ar * SR + akq * 8] = vh;
      *(ushort8v*)&Al[ar * SR + akq * 8] = vl;
    }
    for (int p = 0; p < 2; p++){
      int idx = p * 256 + t; int n = idx >> 2, kq = idx & 3;
      size_t go = (size_t)(n0 + n) * ldW + kBegin + k0 + kq * 8;
      *(ushort8v*)&Bh[n * SR + kq * 8] = *(const ushort8v*)(J.Wh + go);
      *(ushort8v*)&Bl[n * SR + kq * 8] = *(const ushort8v*)(J.Wl + go);
    }
    __syncthreads();
    bf16x8 ah[2], al2[2], bh[4], bl[4];
    for (int f = 0; f < 2; f++){ int o = (wm * 32 + f * 16 + lr) * SR + lk; ah[f] = *(const bf16x8*)&Ah[o]; al2[f] = *(const bf16x8*)&Al[o]; }
    for (int g = 0; g < 4; g++){ int o = (wn * 64 + g * 16 + lr) * SR + lk; bh[g] = *(const bf16x8*)&Bh[o]; bl[g] = *(const bf16x8*)&Bl[o]; }
    for (int f = 0; f < 2; f++)
      for (int g = 0; g < 4; g++){
        acc[f][g] = __builtin_amdgcn_mfma_f32_16x16x32_bf16(ah[f],  bh[g], acc[f][g], 0, 0, 0);
        acc[f][g] = __builtin_amdgcn_mfma_f32_16x16x32_bf16(ah[f],  bl[g], acc[f][g], 0, 0, 0);
        acc[f][g] = __builtin_amdgcn_mfma_f32_16x16x32_bf16(al2[f], bh[g], acc[f][g], 0, 0, 0);
      }
    __syncthreads();
  }
  int rr = (lane >> 4) * 4;
  for (int f = 0; f < 2; f++){
    int gm = m0 + wm * 32 + f * 16 + rr;
    for (int g = 0; g < 4; g++){
      int gn = n0 + wn * 64 + g * 16 + (lane & 15);
      float bv = (MODE != 2 && J.bias) ? J.bias[gn] : 0.f;
      for (int r2 = 0; r2 < 4; r2++){
        float v = acc[f][g][r2] + bv;
        if (MODE == 0) v = fmaxf(v, 0.f);
        Cptr[(size_t)(gm + r2) * ldC + gn] = v;
      }
    }
  }
}

// ---------------- split-K partial reduce ----------------
template<bool RELU>
__global__ __launch_bounds__(256) void reduce_part(
    const float* __restrict__ P, int S,
    const float* __restrict__ bias0, const float* __restrict__ bias1,
    float* __restrict__ outp, int zCount, int ldOut)
{
  const int MN = MROWS * Ddim;
  int idx4 = blockIdx.x * 256 + threadIdx.x;
  int flat = idx4 * 4;
  if (flat >= MN * zCount) return;
  int z = flat / MN; int rem = flat - z * MN;
  int r = rem / Ddim; int c = rem - r * Ddim;
  const float* base = P + (size_t)z * S * MN + rem;
  f32x4 sv = *(const f32x4*)base;
  for (int ss = 1; ss < S; ss++){ f32x4 v = *(const f32x4*)(base + (size_t)ss * MN); sv += v; }
  const float* bp = z ? bias1 : bias0;
  f32x4 bv = *(const f32x4*)(bp + c);
  sv += bv;
  if (RELU) for (int e = 0; e < 4; e++) sv[e] = fmaxf(sv[e], 0.f);
  *(f32x4*)(outp + (size_t)r * ldOut + z * Ddim + c) = sv;
}

// ---------------- fused pair GEMM v5 --------------------------------------------------
// Block: (nq in 0..5, b in 0..3, ig in 0..47).  M = 192 (2 i's x 96 j), N = 128, BK = 64.
// 4 waves (2x2): wave (wm,wn) -> i = ig*2+wm, cols wn*64.. ; wave tile 96x64,
// mfma_f32_32x32x16, acc[3][2] f32x16 (96 AGPR -> combined regs ~210, 2 waves/SIMD).
// vv fragments double-buffered across kh (ds latency hidden under build+MFMA).
// U loads issued BEFORE the DMA so their vmcnt waits don't drain the prefetch queue.
// No setprio.  One barrier per K-tile.
#define KH_STEP(KH, VVC, VVN, UA, UB, PRE) { \
  bf16x8 bfr[2]; \
  int gx = ((KH) * 2 + hsel) * 16; \
  _Pragma("unroll") \
  for (int nf = 0; nf < 2; nf++){ \
    int n = wn * 64 + nf * 32 + l31; \
    bfr[nf] = *(const bf16x8*)((const char*)&Bs[cur][0] + n * 128 + (gx ^ ((n & 7) << 4))); \
  } \
  if (PRE){ \
    int gn = (((KH) + 1) * 2 + hsel) * 16; \
    _Pragma("unroll") \
    for (int mf = 0; mf < 3; mf++){ \
      int j = mf * 32 + l31; \
      VVN[mf] = *(const bf16x8*)((const char*)&Vs[cur][0] + j * 128 + (gn ^ ((j & 7) << 4))); \
    } \
  } \
  bf16x8 afr[3]; \
  _Pragma("unroll") \
  for (int mf = 0; mf < 3; mf++){ \
    ushort8v vb = __builtin_bit_cast(ushort8v, VVC[mf]); \
    ushort8v pk; \
    _Pragma("unroll") \
    for (int e = 0; e < 4; e++) pk[e]   = f2bf(fmaxf(UA[e] + bfbits2f(vb[e]),   0.f)); \
    _Pragma("unroll") \
    for (int e = 0; e < 4; e++) pk[e+4] = f2bf(fmaxf(UB[e] + bfbits2f(vb[e+4]), 0.f)); \
    afr[mf] = __builtin_bit_cast(bf16x8, pk); \
  } \
  _Pragma("unroll") \
  for (int mf = 0; mf < 3; mf++) \
    _Pragma("unroll") \
    for (int nf = 0; nf < 2; nf++) \
      acc[mf][nf] = __builtin_amdgcn_mfma_f32_32x32x16_bf16(afr[mf], bfr[nf], acc[mf][nf], 0, 0, 0); \
}

__global__ __launch_bounds__(256, 2) void pair_gemm5(
    const float* __restrict__ U,            // [MROWS][Hdim] f32, ro_b1 folded
    const unsigned short* __restrict__ Vp,  // per (b,kt): swizzled [96 j][64 k] bf16
    const unsigned short* __restrict__ W2P, // per (nq,kt): swizzled [128 n][64 k] bf16
    const float* __restrict__ b2,           // [Ddim]
    float* __restrict__ out)                // [Bdim*Pdim][Ddim]
{
  __shared__ __align__(16) unsigned short Bs[2][8192]; // 2 x 16 KiB
  __shared__ __align__(16) unsigned short Vs[2][6144]; // 2 x 12 KiB

  int x = blockIdx.x;
  int xcd = x & 7;
  int s = x >> 3;                 // 0..143
  int grp = s / 48;               // 0..2
  int ig  = s - grp * 48;         // 0..47 (consecutive blocks on an XCD share (nq,b))
  int combo = xcd + grp * 8;      // 0..23
  int nq = combo % 6, b = combo / 6;

  int t = threadIdx.x, lane = t & 63, w = t >> 6;
  int wm = w >> 1, wn = w & 1;
  int l31 = lane & 31, hsel = lane >> 5;
  int i = ig * 2 + wm;
  const float* Urow = U + ((size_t)(b * 96 + i)) * Hdim + hsel * 8;

  f32x16 acc[3][2] = {};

  const unsigned short* srcB0 = W2P + (size_t)(nq * 48) * 8192 + t * 8;
  const unsigned short* srcV0 = Vp  + (size_t)(b  * 48) * 6144 + t * 8;

  // prologue: DMA kt=0
  #pragma unroll
  for (int q = 0; q < 4; q++)
    __builtin_amdgcn_global_load_lds(
        (const __attribute__((address_space(1))) unsigned int*)(srcB0 + q * 2048),
        (__attribute__((address_space(3))) unsigned int*)&Bs[0][q * 2048 + t * 8], 16, 0, 0);
  #pragma unroll
  for (int q = 0; q < 3; q++)
    __builtin_amdgcn_global_load_lds(
        (const __attribute__((address_space(1))) unsigned int*)(srcV0 + q * 2048),
        (__attribute__((address_space(3))) unsigned int*)&Vs[0][q * 2048 + t * 8], 16, 0, 0);
  __syncthreads();

  for (int kt = 0; kt < NKT4; kt++){
    int cur = kt & 1;
    // vv fragments for kh=0 (ds_read, issued first)
    bf16x8 vvA[3], vvB[3];
    {
      int g0 = hsel * 16;
      #pragma unroll
      for (int mf = 0; mf < 3; mf++){
        int j = mf * 32 + l31;
        vvA[mf] = *(const bf16x8*)((const char*)&Vs[cur][0] + j * 128 + (g0 ^ ((j & 7) << 4)));
      }
    }
    // U slices: global loads BEFORE the DMA issue (in-order vmcnt -> cheap waits)
    const float* ub = Urow + kt * 64;
    f32x4 u00 = *(const f32x4*)(ub +  0), u01 = *(const f32x4*)(ub +  4);
    f32x4 u10 = *(const f32x4*)(ub + 16), u11 = *(const f32x4*)(ub + 20);
    f32x4 u20 = *(const f32x4*)(ub + 32), u21 = *(const f32x4*)(ub + 36);
    f32x4 u30 = *(const f32x4*)(ub + 48), u31 = *(const f32x4*)(ub + 52);
    // DMA next K-tile
    if (kt + 1 < NKT4){
      const unsigned short* sB = srcB0 + (size_t)(kt + 1) * 8192;
      const unsigned short* sV = srcV0 + (size_t)(kt + 1) * 6144;
      #pragma unroll
      for (int q = 0; q < 4; q++)
        __builtin_amdgcn_global_load_lds(
            (const __attribute__((address_space(1))) unsigned int*)(sB + q * 2048),
            (__attribute__((address_space(3))) unsigned int*)&Bs[cur ^ 1][q * 2048 + t * 8], 16, 0, 0);
      #pragma unroll
      for (int q = 0; q < 3; q++)
        __builtin_amdgcn_global_load_lds(
            (const __attribute__((address_space(1))) unsigned int*)(sV + q * 2048),
            (__attribute__((address_space(3))) unsigned int*)&Vs[cur ^ 1][q * 2048 + t * 8], 16, 0, 0);
    }
    KH_STEP(0, vvA, vvB, u00, u01, 1)
    KH_STEP(1, vvB, vvA, u10, u11, 1)
    KH_STEP(2, vvA, vvB, u20, u21, 1)
    KH_STEP(3, vvB, vvA, u30, u31, 0)
    __syncthreads();
  }

  // epilogue: row j -> pair p = i*95 + j - (j>i); skip j==i
  size_t outB = (size_t)b * Pdim;
  int colbase = nq * 128 + wn * 64;
  float bc[2];
  #pragma unroll
  for (int nf = 0; nf < 2; nf++) bc[nf] = b2[colbase + nf * 32 + l31];
  #pragma unroll
  for (int mf = 0; mf < 3; mf++){
    #pragma unroll
    for (int reg = 0; reg < 16; reg++){
      int j = mf * 32 + (reg & 3) + 8 * (reg >> 2) + 4 * hsel;
      if (j == i) continue;
      int p = i * 95 + j - (j > i ? 1 : 0);
      float* orow = out + (outB + p) * Ddim + colbase;
      #pragma unroll
      for (int nf = 0; nf < 2; nf++)
        orow[nf * 32 + l31] = acc[mf][nf][reg] + bc[nf];
    }
  }
}

// ---------------- host launch ----------------
extern "C" void kernel_launch(void* const* d_in, const int* in_sizes, int n_in,
                              void* d_out, int out_size, void* d_ws, size_t ws_size,
                              hipStream_t stream)
{
  (void)in_sizes; (void)n_in; (void)out_size;
  const float* h     = (const float*)d_in[0];
  const int*   span  = (const int*)d_in[1];
  const float* ps_w1 = (const float*)d_in[2];
  const float* ps_b1 = (const float*)d_in[3];
  const float* ps_w2 = (const float*)d_in[4];
  const float* ps_b2 = (const float*)d_in[5];
  const float* pe_w1 = (const float*)d_in[6];
  const float* pe_b1 = (const float*)d_in[7];
  const float* pe_w2 = (const float*)d_in[8];
  const float* pe_b2 = (const float*)d_in[9];
  const float* so_w1 = (const float*)d_in[10];
  const float* so_b1 = (const float*)d_in[11];
  const float* so_w2 = (const float*)d_in[12];
  const float* so_b2 = (const float*)d_in[13];
  const float* ro_w1 = (const float*)d_in[14];
  const float* ro_b1 = (const float*)d_in[15];
  const float* ro_w2 = (const float*)d_in[16];
  const float* ro_b2 = (const float*)d_in[17];

  char* ws = (char*)d_ws;
  size_t off = 0;
  auto alloc_us = [&](size_t n)->unsigned short*{
    unsigned short* p = (unsigned short*)(ws + off);
    off += ((n * 2 + 255) & ~(size_t)255);
    return p;
  };
  auto alloc_f = [&](size_t n)->float*{
    float* p = (float*)(ws + off);
    off += ((n * 4 + 255) & ~(size_t)255);
    return p;
  };

  unsigned short* ps1h = alloc_us((size_t)Hdim * Ddim); unsigned short* ps1l = alloc_us((size_t)Hdim * Ddim);
  unsigned short* ps2h = alloc_us((size_t)Ddim * Hdim); unsigned short* ps2l = alloc_us((size_t)Ddim * Hdim);
  unsigned short* pe1h = alloc_us((size_t)Hdim * Ddim); unsigned short* pe1l = alloc_us((size_t)Hdim * Ddim);
  unsigned short* pe2h = alloc_us((size_t)Ddim * Hdim); unsigned short* pe2l = alloc_us((size_t)Ddim * Hdim);
  unsigned short* so1h = alloc_us((size_t)Hdim * 2 * Ddim); unsigned short* so1l = alloc_us((size_t)Hdim * 2 * Ddim);
  unsigned short* so2h = alloc_us((size_t)Ddim * Hdim); unsigned short* so2l = alloc_us((size_t)Ddim * Hdim);
  unsigned short* ro1h = alloc_us((size_t)Hdim * 2 * Ddim); unsigned short* ro1l = alloc_us((size_t)Hdim * 2 * Ddim);
  unsigned short* W2P  = alloc_us((size_t)6 * 48 * 8192);   // 2.36M shorts
  unsigned short* Vp   = alloc_us((size_t)4 * 48 * 6144);   // 1.18M shorts
  float* hg     = alloc_f((size_t)2 * MROWS * Ddim);
  float* mid_s  = alloc_f((size_t)MROWS * Hdim);
  float* mid_e  = alloc_f((size_t)MROWS * Hdim);
  float* cat    = alloc_f((size_t)MROWS * 2 * Ddim);
  float* entity = alloc_f((size_t)MROWS * Ddim);
  float* Ubuf   = alloc_f((size_t)MROWS * Hdim);
  float* Vbuf   = alloc_f((size_t)MROWS * Hdim);
  const size_t MN = (size_t)MROWS * Ddim;
  float* P2 = alloc_f(8 * MN);
  float* P3 = alloc_f(4 * MN);
  if (off > ws_size) return;

  dim3 tb(256);

  // merged weight transposes (7 jobs)
  {
    TJobs JJ;
    int base = 0;
    auto add = [&](int idx, const float* W, unsigned short* Th, unsigned short* Tl, int K, int N){
      JJ.j[idx] = TJob{W, Th, Tl, K, N, base};
      base += (N / 64) * (K / 64);
    };
    add(0, ps_w1, ps1h, ps1l, Ddim, Hdim);
    add(1, ps_w2, ps2h, ps2l, Hdim, Ddim);
    add(2, pe_w1, pe1h, pe1l, Ddim, Hdim);
    add(3, pe_w2, pe2h, pe2l, Hdim, Ddim);
    add(4, so_w1, so1h, so1l, 2 * Ddim, Hdim);
    add(5, so_w2, so2h, so2l, Hdim, Ddim);
    add(6, ro_w1, ro1h, ro1l, 2 * Ddim, Hdim);
    transpose_multi<<<base, tb, 0, stream>>>(JJ);
  }
  pack_w2<<<dim3(NKT4, 6), tb, 0, stream>>>(ro_w2, W2P);

  gather_rows<<<2 * MROWS, tb, 0, stream>>>(h, span, hg);

  // L1: start/end first linear (merged), M=384 N=3072 K=768
  {
    GJob j0{hg,                      ps1h, ps1l, ps_b1, mid_s};
    GJob j1{hg + (size_t)MROWS*Ddim, pe1h, pe1l, pe_b1, mid_e};
    gemm_ms<0,1><<<dim3(Hdim/128, MROWS/64, 2), tb, 0, stream>>>(j0, j1, Ddim, Ddim, Hdim, Ddim, 0);
  }
  // L2: start/end second linear (merged, split-K=4) -> partials
  {
    GJob j0{mid_s, ps2h, ps2l, nullptr, P2};
    GJob j1{mid_e, pe2h, pe2l, nullptr, P2 + 4*MN};
    gemm_ms<2,4><<<dim3(Ddim/128, MROWS/64, 8), tb, 0, stream>>>(j0, j1, Hdim, Hdim, Ddim, Hdim/4, MN);
  }
  reduce_part<true><<<(2*(int)MN)/1024, tb, 0, stream>>>(P2, 4, ps_b2, pe_b2, cat, 2, 2*Ddim);
  // so1: M=384 N=3072 K=1536
  {
    GJob j0{cat, so1h, so1l, so_b1, mid_s};
    gemm_ms<0,1><<<dim3(Hdim/128, MROWS/64, 1), tb, 0, stream>>>(j0, j0, 2*Ddim, 2*Ddim, Hdim, 2*Ddim, 0);
  }
  // so2: split-K=4 -> partials (no relu on entity)
  {
    GJob j0{mid_s, so2h, so2l, nullptr, P3};
    gemm_ms<2,4><<<dim3(Ddim/128, MROWS/64, 4), tb, 0, stream>>>(j0, j0, Hdim, Hdim, Ddim, Hdim/4, MN);
  }
  reduce_part<false><<<((int)MN)/1024, tb, 0, stream>>>(P3, 4, so_b2, so_b2, entity, 1, Ddim);
  // U = entity @ ro_w1_top + ro_b1 ; V = entity @ ro_w1_bot (merged)
  {
    GJob j0{entity, ro1h,        ro1l,        ro_b1,   Ubuf};
    GJob j1{entity, ro1h + Ddim, ro1l + Ddim, 2*Ddim == 0 ? nullptr : nullptr, Vbuf};
    gemm_ms<1,1><<<dim3(Hdim/128, MROWS/64, 2), tb, 0, stream>>>(j0, j1, Ddim, 2*Ddim, Hdim, Ddim, 0);
  }
  pack_v<<<dim3(NKT4, Bdim), tb, 0, stream>>>(Vbuf, Vp);

  // fused pair GEMM v5
  pair_gemm5<<<1152, tb, 0, stream>>>(Ubuf, Vp, W2P, ro_b2, (float*)d_out);
}

// Round 7
// 490.629 us; speedup vs baseline: 1.0240x; 1.0240x over previous
//
#include <hip/hip_runtime.h>
#include <hip/hip_bf16.h>

// ---- problem dims (fixed) ----
#define Bdim 4
#define Ldim 512
#define Ddim 768
#define Kspan 96
#define Hdim 3072
#define Pdim 9120      // Kspan*(Kspan-1)
#define MROWS 384      // Bdim*Kspan
#define NT6 96         // Hdim/32: K-tiles for pair kernel (BK=32)

typedef __bf16 bf16x8 __attribute__((ext_vector_type(8)));
typedef float f32x4 __attribute__((ext_vector_type(4)));
typedef float f32x16 __attribute__((ext_vector_type(16)));
typedef unsigned short ushort8v __attribute__((ext_vector_type(8)));

static __device__ __forceinline__ unsigned short f2bf(float x){
  return __builtin_bit_cast(unsigned short, (__bf16)x);
}
static __device__ __forceinline__ float bf2f(unsigned short u){
  return (float)__builtin_bit_cast(__bf16, u);
}
static __device__ __forceinline__ float bfbits2f(unsigned short u){
  return __builtin_bit_cast(float, (unsigned)u << 16);
}

// ---------------- merged transpose+split: W[K][N] f32 -> WT[N][K] bf16 hi+lo -------------
struct TJob { const float* W; unsigned short* Th; unsigned short* Tl; int K; int N; int base; };
struct TJobs { TJob j[7]; };

__global__ __launch_bounds__(256) void transpose_multi(TJobs JJ)
{
  int x = blockIdx.x;
  int ji = 0;
  #pragma unroll
  for (int q = 1; q < 7; q++) if (x >= JJ.j[q].base) ji = q;
  TJob J = JJ.j[ji];
  int local = x - J.base;
  int tilesX = J.N >> 6;
  int bx = local % tilesX, by = local / tilesX;
  __shared__ float tile[64][65];
  int k0 = by * 64, n0 = bx * 64;
  int c = threadIdx.x & 63, r0 = threadIdx.x >> 6;
  for (int p = 0; p < 16; p++){
    int r = r0 + p * 4;
    tile[c][r] = J.W[(size_t)(k0 + r) * J.N + n0 + c];
  }
  __syncthreads();
  for (int p = 0; p < 16; p++){
    int n = r0 + p * 4;
    float xv = tile[n][c];
    unsigned short h = f2bf(xv);
    size_t o = (size_t)(n0 + n) * J.K + k0 + c;
    J.Th[o] = h;
    J.Tl[o] = f2bf(xv - bf2f(h));
  }
}

// ---------------- pack ro_w2 [Hdim][Ddim] f32 -> W2P bf16, pre-swizzled ------------------
// Tile (nq in 0..5, kt in 0..95): 128 n-rows x 32 k shorts, 64B rows.
// Phys short o: n = o>>5, slot = (o>>3)&3, e = o&7; logical granule g = slot ^ ((n>>1)&3).
__global__ __launch_bounds__(256) void pack_w2(
    const float* __restrict__ W, unsigned short* __restrict__ W2P)
{
  __shared__ float tile[32][129];
  int kt = blockIdx.x, nq = blockIdx.y, t = threadIdx.x;
  for (int q = 0; q < 16; q++){
    int flat = q * 256 + t;             // 0..4095
    int kl = flat >> 7, n = flat & 127;
    tile[kl][n] = W[(size_t)(kt * 32 + kl) * Ddim + nq * 128 + n];
  }
  __syncthreads();
  unsigned short* outp = W2P + (size_t)(nq * 96 + kt) * 4096;
  for (int q = 0; q < 16; q++){
    int o = q * 256 + t;
    int n = o >> 5, slot = (o >> 3) & 3, e = o & 7;
    int kl = (slot ^ ((n >> 1) & 3)) * 8 + e;
    outp[o] = f2bf(tile[kl][n]);
  }
}

// ---------------- gather h rows at span indices (fp32 copy) ----------------
__global__ __launch_bounds__(256) void gather_rows(
    const float* __restrict__ h, const int* __restrict__ span, float* __restrict__ hg)
{
  int x = blockIdx.x;            // 0 .. 2*MROWS-1
  int sel = (x >= MROWS) ? 1 : 0;
  int r = x - sel * MROWS;
  int b = r / Kspan, k = r - b * Kspan;
  int idx = span[(b * Kspan + k) * 2 + sel];
  const float* src = h + ((size_t)b * Ldim + idx) * Ddim;
  float* dst = hg + (size_t)x * Ddim;
  for (int d = threadIdx.x; d < Ddim; d += 256) dst[d] = src[d];
}

// ---------------- split-bf16 GEMM (multi-job + optional split-K) ------------------------
// MODE 0: relu(acc+bias) f32; MODE 1: acc+bias f32; MODE 2: raw split-K partial;
// MODE 5: job0 -> f32 acc+bias, job1 -> bf16 raw (for U/V with packed V output).
struct GJob {
  const float* A;
  const unsigned short* Wh;
  const unsigned short* Wl;
  const float* bias;
  float* C;
};

template<int MODE, int SPLIT>
__global__ __launch_bounds__(256) void gemm_ms(
    GJob j0, GJob j1, int ldA, int ldW, int ldC, int kLen, size_t csz)
{
  constexpr int SR = 40;
  __shared__ __align__(16) unsigned short Ah[64 * SR], Al[64 * SR];
  __shared__ __align__(16) unsigned short Bh[128 * SR], Bl[128 * SR];
  int zj, s;
  if (SPLIT == 1){ zj = blockIdx.z; s = 0; }
  else { zj = blockIdx.z / SPLIT; s = blockIdx.z % SPLIT; }
  const GJob J = zj ? j1 : j0;
  int kBegin = s * kLen;
  float* Cptr = (MODE == 2) ? (J.C + (size_t)s * csz) : J.C;

  int m0 = blockIdx.y * 64, n0 = blockIdx.x * 128;
  int t = threadIdx.x, lane = t & 63, wid = t >> 6;
  int wm = wid >> 1, wn = wid & 1;
  int lr = lane & 15, lk = (lane >> 4) * 8;
  f32x4 acc[2][4] = {};
  int ar = t >> 2, akq = t & 3;
  for (int k0 = 0; k0 < kLen; k0 += 32){
    {
      const float* sp = J.A + (size_t)(m0 + ar) * ldA + kBegin + k0 + akq * 8;
      f32x4 x0 = *(const f32x4*)sp, x1 = *(const f32x4*)(sp + 4);
      ushort8v vh, vl;
      for (int e = 0; e < 4; e++){ float x = x0[e]; unsigned short hh = f2bf(x); vh[e] = hh; vl[e] = f2bf(x - bf2f(hh)); }
      for (int e = 0; e < 4; e++){ float x = x1[e]; unsigned short hh = f2bf(x); vh[e+4] = hh; vl[e+4] = f2bf(x - bf2f(hh)); }
      *(ushort8v*)&Ah[ar * SR + akq * 8] = vh;
      *(ushort8v*)&Al[ar * SR + akq * 8] = vl;
    }
    for (int p = 0; p < 2; p++){
      int idx = p * 256 + t; int n = idx >> 2, kq = idx & 3;
      size_t go = (size_t)(n0 + n) * ldW + kBegin + k0 + kq * 8;
      *(ushort8v*)&Bh[n * SR + kq * 8] = *(const ushort8v*)(J.Wh + go);
      *(ushort8v*)&Bl[n * SR + kq * 8] = *(const ushort8v*)(J.Wl + go);
    }
    __syncthreads();
    bf16x8 ah[2], al2[2], bh[4], bl[4];
    for (int f = 0; f < 2; f++){ int o = (wm * 32 + f * 16 + lr) * SR + lk; ah[f] = *(const bf16x8*)&Ah[o]; al2[f] = *(const bf16x8*)&Al[o]; }
    for (int g = 0; g < 4; g++){ int o = (wn * 64 + g * 16 + lr) * SR + lk; bh[g] = *(const bf16x8*)&Bh[o]; bl[g] = *(const bf16x8*)&Bl[o]; }
    for (int f = 0; f < 2; f++)
      for (int g = 0; g < 4; g++){
        acc[f][g] = __builtin_amdgcn_mfma_f32_16x16x32_bf16(ah[f],  bh[g], acc[f][g], 0, 0, 0);
        acc[f][g] = __builtin_amdgcn_mfma_f32_16x16x32_bf16(ah[f],  bl[g], acc[f][g], 0, 0, 0);
        acc[f][g] = __builtin_amdgcn_mfma_f32_16x16x32_bf16(al2[f], bh[g], acc[f][g], 0, 0, 0);
      }
    __syncthreads();
  }
  int rr = (lane >> 4) * 4;
  for (int f = 0; f < 2; f++){
    int gm = m0 + wm * 32 + f * 16 + rr;
    for (int g = 0; g < 4; g++){
      int gn = n0 + wn * 64 + g * 16 + (lane & 15);
      float bv = ((MODE == 0 || MODE == 1) && J.bias) ? J.bias[gn] : 0.f;
      if (MODE == 5 && zj == 0) bv = J.bias[gn];
      for (int r2 = 0; r2 < 4; r2++){
        float v = acc[f][g][r2] + bv;
        if (MODE == 0) v = fmaxf(v, 0.f);
        if (MODE == 5 && zj == 1){
          ((unsigned short*)J.C)[(size_t)(gm + r2) * ldC + gn] = f2bf(v);
        } else {
          Cptr[(size_t)(gm + r2) * ldC + gn] = v;
        }
      }
    }
  }
}

// ---------------- split-K partial reduce ----------------
template<bool RELU>
__global__ __launch_bounds__(256) void reduce_part(
    const float* __restrict__ P, int S,
    const float* __restrict__ bias0, const float* __restrict__ bias1,
    float* __restrict__ outp, int zCount, int ldOut)
{
  const int MN = MROWS * Ddim;
  int idx4 = blockIdx.x * 256 + threadIdx.x;
  int flat = idx4 * 4;
  if (flat >= MN * zCount) return;
  int z = flat / MN; int rem = flat - z * MN;
  int r = rem / Ddim; int c = rem - r * Ddim;
  const float* base = P + (size_t)z * S * MN + rem;
  f32x4 sv = *(const f32x4*)base;
  for (int ss = 1; ss < S; ss++){ f32x4 v = *(const f32x4*)(base + (size_t)ss * MN); sv += v; }
  const float* bp = z ? bias1 : bias0;
  f32x4 bv = *(const f32x4*)(bp + c);
  sv += bv;
  if (RELU) for (int e = 0; e < 4; e++) sv[e] = fmaxf(sv[e], 0.f);
  *(f32x4*)(outp + (size_t)r * ldOut + z * Ddim + c) = sv;
}

// ---------------- fused pair GEMM v7 --------------------------------------------------
// Block: (nq in 0..5, b, ig).  M = 192 (2 i's x 96 j), N = 128, BK = 32, 96 K-tiles.
// 4 waves (wm: i, wn: 64-col half), wave tile 96x64, acc[3][2] f32x16 (96 AGPR).
// A built ONCE per block cooperatively into LDS (R = nq = 6), V prefetched to regs one
// tile ahead, U staged in LDS once (broadcast reads), B via global_load_lds from
// pre-swizzled W2P.  DEPTH-1 B prefetch (race-free: DMA only ever targets the buffer not
// being read this phase; end-of-phase barrier drains it).  Swizzle: slot = g ^ ((row>>1)&3)
// -- conflict-free for b128 in 8-lane groups with 64B rows.  2 blocks/CU (64 KiB LDS).
__global__ __launch_bounds__(256, 2) void pair_gemm7(
    const float* __restrict__ U,            // [MROWS][Hdim] f32, ro_b1 folded
    const unsigned short* __restrict__ Vp,  // [MROWS][Hdim] bf16 linear
    const unsigned short* __restrict__ W2P, // per (nq,kt): swizzled [128 n][32 k] bf16
    const float* __restrict__ b2,           // [Ddim]
    float* __restrict__ out)                // [Bdim*Pdim][Ddim]
{
  __shared__ __align__(16) unsigned short As[2][192 * 32]; // 2 x 12 KiB
  __shared__ __align__(16) unsigned short Bs[2][128 * 32]; // 2 x 8 KiB
  __shared__ __align__(16) float Uls[2][Hdim];             // 24 KiB

  int x = blockIdx.x;
  int xcd = x & 7;
  int s = x >> 3;                 // 0..143
  int grp = s / 48;
  int ig  = s - grp * 48;
  int combo = xcd + grp * 8;      // 0..23
  int nq = combo % 6, b = combo / 6;

  int t = threadIdx.x, lane = t & 63, w = t >> 6;
  int wm = w >> 1, wn = w & 1;
  int l31 = lane & 31, hsel = lane >> 5;
  int i0 = ig * 2, i = i0 + wm;

  // builder: 3 items q=0..2, row = t/4 + 64q (0..191), fixed granule bg = t&3
  int brow = t >> 2, bg = t & 3;
  int vj[3];
  #pragma unroll
  for (int q = 0; q < 3; q++){
    int r = brow + 64 * q;
    vj[q] = (r >= 96) ? (r - 96) : r;
  }

  f32x16 acc[3][2] = {};
  ushort8v vE[3], vO[3];

  auto loadV = [&](int kt, ushort8v* dst){
    #pragma unroll
    for (int q = 0; q < 3; q++)
      dst[q] = *(const ushort8v*)(Vp + (size_t)(b * 96 + vj[q]) * Hdim + kt * 32 + bg * 8);
  };
  auto issueB = [&](int kt, int buf){
    const unsigned short* src = W2P + (size_t)(nq * 96 + kt) * 4096 + t * 8;
    unsigned short* d0 = (buf == 0) ? &Bs[0][t * 8] : &Bs[1][t * 8];
    __builtin_amdgcn_global_load_lds(
        (const __attribute__((address_space(1))) unsigned int*)src,
        (__attribute__((address_space(3))) unsigned int*)d0, 16, 0, 0);
    __builtin_amdgcn_global_load_lds(
        (const __attribute__((address_space(1))) unsigned int*)(src + 2048),
        (__attribute__((address_space(3))) unsigned int*)(d0 + 2048), 16, 0, 0);
  };
  auto build = [&](int kt, int buf, ushort8v* vsrc){
    #pragma unroll
    for (int q = 0; q < 3; q++){
      int r = brow + 64 * q;
      int ihalf = (r >= 96) ? 1 : 0;
      const float* up = &Uls[ihalf][kt * 32 + bg * 8];
      f32x4 ua = *(const f32x4*)up;
      f32x4 ub = *(const f32x4*)(up + 4);
      ushort8v vv = vsrc[q];
      ushort8v pk;
      #pragma unroll
      for (int e = 0; e < 4; e++) pk[e]     = f2bf(fmaxf(ua[e] + bfbits2f(vv[e]),     0.f));
      #pragma unroll
      for (int e = 0; e < 4; e++) pk[e + 4] = f2bf(fmaxf(ub[e] + bfbits2f(vv[e + 4]), 0.f));
      unsigned short* dp = (buf == 0) ? &As[0][0] : &As[1][0];
      *(ushort8v*)(dp + r * 32 + ((bg ^ ((r >> 1) & 3)) << 3)) = pk;
    }
  };
  auto compute = [&](int buf){
    const unsigned short* ap = (buf == 0) ? &As[0][0] : &As[1][0];
    const unsigned short* bp = (buf == 0) ? &Bs[0][0] : &Bs[1][0];
    #pragma unroll
    for (int kh = 0; kh < 2; kh++){
      int g = kh * 2 + hsel;
      bf16x8 bfr[2], afr[3];
      #pragma unroll
      for (int nf = 0; nf < 2; nf++){
        int n = wn * 64 + nf * 32 + l31;
        bfr[nf] = *(const bf16x8*)(bp + n * 32 + ((g ^ ((n >> 1) & 3)) << 3));
      }
      #pragma unroll
      for (int mf = 0; mf < 3; mf++){
        int r = wm * 96 + mf * 32 + l31;
        afr[mf] = *(const bf16x8*)(ap + r * 32 + ((g ^ ((r >> 1) & 3)) << 3));
      }
      #pragma unroll
      for (int mf = 0; mf < 3; mf++)
        #pragma unroll
        for (int nf = 0; nf < 2; nf++)
          acc[mf][nf] = __builtin_amdgcn_mfma_f32_32x32x16_bf16(afr[mf], bfr[nf], acc[mf][nf], 0, 0, 0);
    }
  };

  // prologue: stage U rows into LDS (coalesced), DMA Bs[0], prefetch V(0), V(1)
  loadV(0, vE);
  issueB(0, 0);
  {
    const float* u0 = U + (size_t)(b * 96 + i0) * Hdim;
    for (int q = t; q < 2 * (Hdim / 4); q += 256){
      int r = q / (Hdim / 4), c = q - r * (Hdim / 4);
      *(f32x4*)&Uls[r][c * 4] = *(const f32x4*)(u0 + (size_t)r * Hdim + c * 4);
    }
  }
  __syncthreads();               // Uls + Bs[0] ready
  build(0, 0, vE);
  loadV(1, vO);
  __syncthreads();               // As[0] ready

  for (int kt = 0; kt < NT6; kt += 2){
    // even tile kt: compute buffers 0; prefetch tile kt+1 -> buffers 1
    if (kt + 1 < NT6) issueB(kt + 1, 1);
    if (kt + 2 < NT6) loadV(kt + 2, vE);
    if (kt + 1 < NT6) build(kt + 1, 1, vO);
    compute(0);
    __syncthreads();             // drains B DMA into Bs[1]; As[1] writes visible
    // odd tile kt+1: compute buffers 1; prefetch tile kt+2 -> buffers 0
    int ko = kt + 1;
    if (ko + 1 < NT6) issueB(ko + 1, 0);
    if (ko + 2 < NT6) loadV(ko + 2, vO);
    if (ko + 1 < NT6) build(ko + 1, 0, vE);
    compute(1);
    __syncthreads();
  }

  // epilogue: wave wm -> i; row j -> pair p = i*95 + j - (j>i); skip j==i
  size_t outB = (size_t)b * Pdim;
  int colbase = nq * 128 + wn * 64;
  float bc[2];
  #pragma unroll
  for (int nf = 0; nf < 2; nf++) bc[nf] = b2[colbase + nf * 32 + l31];
  #pragma unroll
  for (int mf = 0; mf < 3; mf++){
    #pragma unroll
    for (int reg = 0; reg < 16; reg++){
      int j = mf * 32 + (reg & 3) + 8 * (reg >> 2) + 4 * hsel;
      if (j == i) continue;
      int p = i * 95 + j - (j > i ? 1 : 0);
      float* orow = out + (outB + p) * Ddim + colbase;
      #pragma unroll
      for (int nf = 0; nf < 2; nf++)
        orow[nf * 32 + l31] = acc[mf][nf][reg] + bc[nf];
    }
  }
}

// ---------------- host launch ----------------
extern "C" void kernel_launch(void* const* d_in, const int* in_sizes, int n_in,
                              void* d_out, int out_size, void* d_ws, size_t ws_size,
                              hipStream_t stream)
{
  (void)in_sizes; (void)n_in; (void)out_size;
  const float* h     = (const float*)d_in[0];
  const int*   span  = (const int*)d_in[1];
  const float* ps_w1 = (const float*)d_in[2];
  const float* ps_b1 = (const float*)d_in[3];
  const float* ps_w2 = (const float*)d_in[4];
  const float* ps_b2 = (const float*)d_in[5];
  const float* pe_w1 = (const float*)d_in[6];
  const float* pe_b1 = (const float*)d_in[7];
  const float* pe_w2 = (const float*)d_in[8];
  const float* pe_b2 = (const float*)d_in[9];
  const float* so_w1 = (const float*)d_in[10];
  const float* so_b1 = (const float*)d_in[11];
  const float* so_w2 = (const float*)d_in[12];
  const float* so_b2 = (const float*)d_in[13];
  const float* ro_w1 = (const float*)d_in[14];
  const float* ro_b1 = (const float*)d_in[15];
  const float* ro_w2 = (const float*)d_in[16];
  const float* ro_b2 = (const float*)d_in[17];

  char* ws = (char*)d_ws;
  size_t off = 0;
  auto alloc_us = [&](size_t n)->unsigned short*{
    unsigned short* p = (unsigned short*)(ws + off);
    off += ((n * 2 + 255) & ~(size_t)255);
    return p;
  };
  auto alloc_f = [&](size_t n)->float*{
    float* p = (float*)(ws + off);
    off += ((n * 4 + 255) & ~(size_t)255);
    return p;
  };

  unsigned short* ps1h = alloc_us((size_t)Hdim * Ddim); unsigned short* ps1l = alloc_us((size_t)Hdim * Ddim);
  unsigned short* ps2h = alloc_us((size_t)Ddim * Hdim); unsigned short* ps2l = alloc_us((size_t)Ddim * Hdim);
  unsigned short* pe1h = alloc_us((size_t)Hdim * Ddim); unsigned short* pe1l = alloc_us((size_t)Hdim * Ddim);
  unsigned short* pe2h = alloc_us((size_t)Ddim * Hdim); unsigned short* pe2l = alloc_us((size_t)Ddim * Hdim);
  unsigned short* so1h = alloc_us((size_t)Hdim * 2 * Ddim); unsigned short* so1l = alloc_us((size_t)Hdim * 2 * Ddim);
  unsigned short* so2h = alloc_us((size_t)Ddim * Hdim); unsigned short* so2l = alloc_us((size_t)Ddim * Hdim);
  unsigned short* ro1h = alloc_us((size_t)Hdim * 2 * Ddim); unsigned short* ro1l = alloc_us((size_t)Hdim * 2 * Ddim);
  unsigned short* W2P  = alloc_us((size_t)6 * 96 * 4096);   // 2.36M shorts
  unsigned short* Vp   = alloc_us((size_t)MROWS * Hdim);    // 1.18M shorts (bf16 V)
  float* hg     = alloc_f((size_t)2 * MROWS * Ddim);
  float* mid_s  = alloc_f((size_t)MROWS * Hdim);
  float* mid_e  = alloc_f((size_t)MROWS * Hdim);
  float* cat    = alloc_f((size_t)MROWS * 2 * Ddim);
  float* entity = alloc_f((size_t)MROWS * Ddim);
  float* Ubuf   = alloc_f((size_t)MROWS * Hdim);
  const size_t MN = (size_t)MROWS * Ddim;
  float* P2 = alloc_f(8 * MN);
  float* P3 = alloc_f(8 * MN);
  if (off > ws_size) return;

  dim3 tb(256);

  // merged weight transposes (7 jobs)
  {
    TJobs JJ;
    int base = 0;
    auto add = [&](int idx, const float* W, unsigned short* Th, unsigned short* Tl, int K, int N){
      JJ.j[idx] = TJob{W, Th, Tl, K, N, base};
      base += (N / 64) * (K / 64);
    };
    add(0, ps_w1, ps1h, ps1l, Ddim, Hdim);
    add(1, ps_w2, ps2h, ps2l, Hdim, Ddim);
    add(2, pe_w1, pe1h, pe1l, Ddim, Hdim);
    add(3, pe_w2, pe2h, pe2l, Hdim, Ddim);
    add(4, so_w1, so1h, so1l, 2 * Ddim, Hdim);
    add(5, so_w2, so2h, so2l, Hdim, Ddim);
    add(6, ro_w1, ro1h, ro1l, 2 * Ddim, Hdim);
    transpose_multi<<<base, tb, 0, stream>>>(JJ);
  }
  pack_w2<<<dim3(NT6, 6), tb, 0, stream>>>(ro_w2, W2P);

  gather_rows<<<2 * MROWS, tb, 0, stream>>>(h, span, hg);

  // L1: start/end first linear (merged), M=384 N=3072 K=768
  {
    GJob j0{hg,                      ps1h, ps1l, ps_b1, mid_s};
    GJob j1{hg + (size_t)MROWS*Ddim, pe1h, pe1l, pe_b1, mid_e};
    gemm_ms<0,1><<<dim3(Hdim/128, MROWS/64, 2), tb, 0, stream>>>(j0, j1, Ddim, Ddim, Hdim, Ddim, 0);
  }
  // L2: start/end second linear (merged, split-K=4) -> partials
  {
    GJob j0{mid_s, ps2h, ps2l, nullptr, P2};
    GJob j1{mid_e, pe2h, pe2l, nullptr, P2 + 4*MN};
    gemm_ms<2,4><<<dim3(Ddim/128, MROWS/64, 8), tb, 0, stream>>>(j0, j1, Hdim, Hdim, Ddim, Hdim/4, MN);
  }
  reduce_part<true><<<(2*(int)MN)/1024, tb, 0, stream>>>(P2, 4, ps_b2, pe_b2, cat, 2, 2*Ddim);
  // so1: M=384 N=3072 K=1536
  {
    GJob j0{cat, so1h, so1l, so_b1, mid_s};
    gemm_ms<0,1><<<dim3(Hdim/128, MROWS/64, 1), tb, 0, stream>>>(j0, j0, 2*Ddim, 2*Ddim, Hdim, 2*Ddim, 0);
  }
  // so2: split-K=8 -> partials (no relu on entity)
  {
    GJob j0{mid_s, so2h, so2l, nullptr, P3};
    gemm_ms<2,8><<<dim3(Ddim/128, MROWS/64, 8), tb, 0, stream>>>(j0, j0, Hdim, Hdim, Ddim, Hdim/8, MN);
  }
  reduce_part<false><<<((int)MN)/1024, tb, 0, stream>>>(P3, 8, so_b2, so_b2, entity, 1, Ddim);
  // U = entity @ ro_w1_top + ro_b1 (f32) ; V = entity @ ro_w1_bot (bf16 packed) — MODE 5
  {
    GJob j0{entity, ro1h,        ro1l,        ro_b1,  Ubuf};
    GJob j1{entity, ro1h + Ddim, ro1l + Ddim, nullptr, (float*)Vp};
    gemm_ms<5,1><<<dim3(Hdim/128, MROWS/64, 2), tb, 0, stream>>>(j0, j1, Ddim, 2*Ddim, Hdim, Ddim, 0);
  }

  // fused pair GEMM v7
  pair_gemm7<<<1152, tb, 0, stream>>>(Ubuf, Vp, W2P, ro_b2, (float*)d_out);
}